// Round 2
// baseline (335.566 us; speedup 1.0000x reference)
//
#include <hip/hip_runtime.h>
#include <hip/hip_fp16.h>

#define F 64
#define NBMAX 1024     // max dst-buckets (256 nodes each) -> supports N <= 262144
#define CHUNK 4096     // edges per partition virtual-block
#define CAPSH 13       // bucket capacity = 8192 slots
#define CAP (1 << CAPSH)
#define MM2 64         // rows per P1-mm virtual block
#define GMN 64         // nodes per P3 virtual block

// ---------------- device-scope grid barrier (persistent-kernel pattern) ----
// Safe because grid is sized to guaranteed co-residency (occupancy API) and
// every block reaches every barrier (phase loops may simply be empty).
__device__ __forceinline__ void gbar(unsigned* ctr, unsigned nblk) {
    __syncthreads();
    if (threadIdx.x == 0) {
        __threadfence();                      // release prior global writes
        atomicAdd(ctr, 1u);                   // device-scope by default
        while (__hip_atomic_load(ctr, __ATOMIC_RELAXED, __HIP_MEMORY_SCOPE_AGENT) < nblk)
            __builtin_amdgcn_s_sleep(2);
        __threadfence();                      // acquire others' writes
    }
    __syncthreads();
}

// accumulate 4x half2 into 8 fp32 with per-row weight (cvt+fma: same VALU
// count as cvt+add — this is how dinv[src] scaling becomes free)
__device__ __forceinline__ void acc8f(float* a, const uint4& u, float w) {
    const __half2* hp = reinterpret_cast<const __half2*>(&u);
#pragma unroll
    for (int q = 0; q < 4; ++q) {
        float2 f = __half22float2(hp[q]);
        a[2 * q]     += f.x * w;
        a[2 * q + 1] += f.y * w;
    }
}

// ================= FUSED A+B+C ===========================================
// P1: edge partition into dst-buckets  +  g1 = x@W1 (fp16, unscaled)
// P2: per-bucket CSR build + desc(start,deg,dinv) + dinvf table (NO g1 rescale)
// P3: out1 = relu(dinv_v*(sum dinv_s*g1[s] + dinv_v*g1[v]) + b1);
//     g2 = (out1@W2)*dinv   (fused gather+MM)
__global__ __launch_bounds__(256, 4) void fused_abc(
        const int* __restrict__ src, const int* __restrict__ dst,
        unsigned* __restrict__ bar, unsigned* __restrict__ bcnt,
        unsigned* __restrict__ part, int E, int NB, int PG, int NVB1,
        const float* __restrict__ Xf, const float* __restrict__ W1,
        __half2* __restrict__ G1, uint4* __restrict__ desc,
        int* __restrict__ csr_src, float* __restrict__ dinvf,
        const float* __restrict__ b1f, const float* __restrict__ W2,
        __half* __restrict__ G2, int N, int NVB3) {
    __shared__ float4 smem4[2112];            // 33792 B union (4 blocks/CU)
    __shared__ unsigned sh_vb;
    const int t = threadIdx.x;
    const unsigned gsz = gridDim.x;
    const uint4* G1r = reinterpret_cast<const uint4*>(G1);

    // ================= P1 (work-stealing over partition + mm vblocks) ====
    for (;;) {
        if (t == 0) sh_vb = atomicAdd(&bar[2], 1u);
        __syncthreads();                      // broadcast + guards smem reuse
        int vb = (int)sh_vb;
        if (vb >= NVB1) break;
        if (vb < PG) {
            // ---- partition role ----
            unsigned* lh    = (unsigned*)smem4;          // NBMAX
            unsigned* lbase = lh + NBMAX;                // NBMAX
            int*      dch   = (int*)(lbase + NBMAX);     // CHUNK dst cache
            int e0 = vb * CHUNK;
            int nch = min(CHUNK, E - e0);
            for (int b = t; b < NB; b += 256) lh[b] = 0;
            for (int i = t; i < nch; i += 256) dch[i] = dst[e0 + i];
            __syncthreads();
            for (int i = t; i < nch; i += 256)
                atomicAdd(&lh[((unsigned)dch[i]) >> 8], 1u);
            __syncthreads();
            for (int b = t; b < NB; b += 256) {
                unsigned c = lh[b];
                lbase[b] = c ? atomicAdd(&bcnt[b], c) : 0u;
                lh[b] = 0;  // reuse as local cursor
            }
            __syncthreads();
            for (int i = t; i < nch; i += 256) {
                unsigned d = (unsigned)dch[i];
                unsigned b = d >> 8;
                unsigned pos = lbase[b] + atomicAdd(&lh[b], 1u);
                if (pos < CAP)
                    part[((size_t)b << CAPSH) + pos] = ((d & 255u) << 24) | (unsigned)src[e0 + i];
            }
        } else {
            // ---- mm role: 64 rows of g1 = x@W1 ----
            float* Ws = (float*)smem4;        // 4096 f (16 KB)
            float* XT = Ws + 4096;            // 64*68 f transposed x-tile
            for (int i = t; i < 1024; i += 256)
                ((float4*)Ws)[i] = ((const float4*)W1)[i];
            int row0 = (vb - PG) * MM2;
            for (int i = t; i < MM2 * 16; i += 256) {
                int r = i >> 4, kc = (i & 15) * 4;
                float4 v = make_float4(0.f, 0.f, 0.f, 0.f);
                int gr = row0 + r;
                if (gr < N) v = *(const float4*)(Xf + (size_t)gr * F + kc);
                XT[(kc + 0) * 68 + r] = v.x;
                XT[(kc + 1) * 68 + r] = v.y;
                XT[(kc + 2) * 68 + r] = v.z;
                XT[(kc + 3) * 68 + r] = v.w;
            }
            __syncthreads();
            int tx = t & 7, ty = t >> 3;      // ty in [0,32): rows 2ty,2ty+1
            float acc0[8], acc1[8];
#pragma unroll
            for (int j = 0; j < 8; ++j) { acc0[j] = 0.f; acc1[j] = 0.f; }
#pragma unroll 4
            for (int k = 0; k < 64; ++k) {
                float2 xr = *(const float2*)&XT[k * 68 + ty * 2];
                float4 w0 = *(const float4*)&Ws[k * 64 + tx * 8];
                float4 w1 = *(const float4*)&Ws[k * 64 + tx * 8 + 4];
                acc0[0] += xr.x * w0.x; acc0[1] += xr.x * w0.y;
                acc0[2] += xr.x * w0.z; acc0[3] += xr.x * w0.w;
                acc0[4] += xr.x * w1.x; acc0[5] += xr.x * w1.y;
                acc0[6] += xr.x * w1.z; acc0[7] += xr.x * w1.w;
                acc1[0] += xr.y * w0.x; acc1[1] += xr.y * w0.y;
                acc1[2] += xr.y * w0.z; acc1[3] += xr.y * w0.w;
                acc1[4] += xr.y * w1.x; acc1[5] += xr.y * w1.y;
                acc1[6] += xr.y * w1.z; acc1[7] += xr.y * w1.w;
            }
#pragma unroll
            for (int i = 0; i < 2; ++i) {
                int gr = row0 + ty * 2 + i;
                if (gr >= N) continue;
                const float* a = i ? acc1 : acc0;
                __half2 h[4];
#pragma unroll
                for (int j = 0; j < 4; ++j)
                    h[j] = __floats2half2_rn(a[2 * j], a[2 * j + 1]);
                *reinterpret_cast<uint4*>(G1 + (size_t)gr * 32 + tx * 4) =
                    *reinterpret_cast<uint4*>(h);
            }
        }
    }
    gbar(&bar[0], gsz);

    // ================= P2: per-bucket CSR build (no g1 rescale) ==========
    for (int vb = blockIdx.x; vb < NB; vb += (int)gsz) {
        unsigned* cnt = (unsigned*)smem4;
        unsigned* off = cnt + 256;
        unsigned* cur = off + 256;
        __syncthreads();
        unsigned m0 = (unsigned)vb << CAPSH;
        unsigned m1 = m0 + min(bcnt[vb], (unsigned)CAP);
        cnt[t] = 0;
        __syncthreads();
        for (unsigned j = m0 + t; j < m1; j += 256)
            atomicAdd(&cnt[part[j] >> 24], 1u);
        __syncthreads();
        off[t] = (cnt[t] + 3u) & ~3u;   // pad segments to 4 slots (16 B)
        __syncthreads();
        for (int o = 1; o < 256; o <<= 1) {
            unsigned add = (t >= o) ? off[t - o] : 0u;
            __syncthreads();
            off[t] += add;
            __syncthreads();
        }
        unsigned excl = (t == 0) ? 0u : off[t - 1];
        __syncthreads();
        off[t] = excl;
        cur[t] = 0;
        int v0 = vb << 8;
        int v = v0 + t;
        float di = rsqrtf((float)(cnt[t] + 1u));
        if (v < N) {
            desc[v] = make_uint4(m0 + excl, cnt[t], __float_as_uint(di), 0u);
            dinvf[v] = di;
        }
        __syncthreads();
        for (unsigned j = m0 + t; j < m1; j += 256) {
            unsigned p = part[j];
            unsigned d = p >> 24;
            unsigned pos = atomicAdd(&cur[d], 1u);
            csr_src[m0 + off[d] + pos] = (int)(p & 0xFFFFFFu);
        }
    }
    gbar(&bar[1], gsz);

    // ================= P3: fused gather + MM (work-stealing) =============
    for (;;) {
        if (t == 0) sh_vb = atomicAdd(&bar[3], 1u);
        __syncthreads();
        int vb = (int)sh_vb;
        if (vb >= NVB3) break;
        float* Ws  = (float*)smem4;                    // 16 KB
        __half* XT = (__half*)(Ws + 4096);             // 64*72 h (9216 B)
        float* dvs = (float*)(XT + 64 * 72);           // 64 f
        for (int i = t; i < 1024; i += 256)
            ((float4*)Ws)[i] = ((const float4*)W2)[i];
        int v0 = vb * GMN;
        {   // ---- phase 1: gather with per-edge dinv[src] fma ----
            int grp = t >> 2, l4 = t & 3;
            int v = v0 + grp;
            float acc[16];
#pragma unroll
            for (int i = 0; i < 16; ++i) acc[i] = 0.f;
            float dv = 0.f;
            if (v < N) {
                uint4 nd = desc[v];
                unsigned r0 = nd.x, r1 = nd.x + nd.y;
                dv = __uint_as_float(nd.z);
                size_t gb = (size_t)v * 8 + l4 * 2;
                uint4 sa = G1r[gb], sb = G1r[gb + 1];   // self-loop: * dinv_v
                acc8f(acc, sa, dv); acc8f(acc + 8, sb, dv);
                unsigned j = r0;
                for (; j + 4 <= r1; j += 4) {
                    int4 s4 = *(const int4*)(csr_src + j);
                    const int s[4] = { s4.x, s4.y, s4.z, s4.w };
                    float dw[4];
                    uint4 u[4][2];
#pragma unroll
                    for (int i = 0; i < 4; ++i) {
                        size_t base = (size_t)s[i] * 8 + l4 * 2;
                        u[i][0] = G1r[base]; u[i][1] = G1r[base + 1];
                        dw[i] = dinvf[s[i]];
                    }
#pragma unroll
                    for (int i = 0; i < 4; ++i) {
                        acc8f(acc, u[i][0], dw[i]);
                        acc8f(acc + 8, u[i][1], dw[i]);
                    }
                }
                for (; j < r1; ++j) {
                    int sj = csr_src[j];
                    float dwj = dinvf[sj];
                    size_t base = (size_t)sj * 8 + l4 * 2;
                    uint4 a = G1r[base], b = G1r[base + 1];
                    acc8f(acc, a, dwj); acc8f(acc + 8, b, dwj);
                }
            }
            if (l4 == 0) dvs[grp] = dv;
            __half h[16];
#pragma unroll
            for (int q = 0; q < 4; ++q) {
                float4 bb = ((const float4*)b1f)[l4 * 4 + q];
                float r0_ = fmaxf(acc[4 * q + 0] * dv + bb.x, 0.f);
                float r1_ = fmaxf(acc[4 * q + 1] * dv + bb.y, 0.f);
                float r2_ = fmaxf(acc[4 * q + 2] * dv + bb.z, 0.f);
                float r3_ = fmaxf(acc[4 * q + 3] * dv + bb.w, 0.f);
                ((__half2*)h)[2 * q + 0] = __floats2half2_rn(r0_, r1_);
                ((__half2*)h)[2 * q + 1] = __floats2half2_rn(r2_, r3_);
            }
            *(uint4*)&XT[grp * 72 + l4 * 16] = ((uint4*)h)[0];
            *(uint4*)&XT[grp * 72 + l4 * 16 + 8] = ((uint4*)h)[1];
        }
        __syncthreads();
        // ---- phase 2: mm (2 rows x 8 cols per thread) ----
        int tx = t & 7, ty = t >> 3;
        const __half2* Xa = (const __half2*)&XT[ty * 72];
        const __half2* Xb = (const __half2*)&XT[(ty + 32) * 72];
        float a0[8], a1[8];
#pragma unroll
        for (int i = 0; i < 8; ++i) { a0[i] = 0.f; a1[i] = 0.f; }
#pragma unroll 4
        for (int k2 = 0; k2 < 32; ++k2) {
            float2 f0 = __half22float2(Xa[k2]);
            float2 f1 = __half22float2(Xb[k2]);
            int k = 2 * k2;
            float4 w00 = *(const float4*)&Ws[k * 64 + tx * 8];
            float4 w01 = *(const float4*)&Ws[k * 64 + tx * 8 + 4];
            float4 w10 = *(const float4*)&Ws[(k + 1) * 64 + tx * 8];
            float4 w11 = *(const float4*)&Ws[(k + 1) * 64 + tx * 8 + 4];
            a0[0] += f0.x * w00.x + f0.y * w10.x; a0[1] += f0.x * w00.y + f0.y * w10.y;
            a0[2] += f0.x * w00.z + f0.y * w10.z; a0[3] += f0.x * w00.w + f0.y * w10.w;
            a0[4] += f0.x * w01.x + f0.y * w11.x; a0[5] += f0.x * w01.y + f0.y * w11.y;
            a0[6] += f0.x * w01.z + f0.y * w11.z; a0[7] += f0.x * w01.w + f0.y * w11.w;
            a1[0] += f1.x * w00.x + f1.y * w10.x; a1[1] += f1.x * w00.y + f1.y * w10.y;
            a1[2] += f1.x * w00.z + f1.y * w10.z; a1[3] += f1.x * w00.w + f1.y * w10.w;
            a1[4] += f1.x * w01.x + f1.y * w11.x; a1[5] += f1.x * w01.y + f1.y * w11.y;
            a1[6] += f1.x * w01.z + f1.y * w11.z; a1[7] += f1.x * w01.w + f1.y * w11.w;
        }
#pragma unroll
        for (int half_ = 0; half_ < 2; ++half_) {
            int r = ty + half_ * 32;
            int v = v0 + r;
            if (v >= N) continue;
            float dv = dvs[r];
            const float* a = half_ ? a1 : a0;
            __half2 h[4];
#pragma unroll
            for (int q = 0; q < 4; ++q)
                h[q] = __floats2half2_rn(a[2 * q] * dv, a[2 * q + 1] * dv);
            *(uint4*)(G2 + (size_t)v * F + tx * 8) = *reinterpret_cast<uint4*>(h);
        }
    }
}

// ---- D: final gather: out[v] = dinv[v]*(sum g2[s] + g2[v]) + b2 ; fp32 out ----
#define ACCUM8(u) { \
    const __half2* hp = reinterpret_cast<const __half2*>(&(u)); \
    _Pragma("unroll") \
    for (int q = 0; q < 4; ++q) { \
        float2 f = __half22float2(hp[q]); \
        acc[2 * q] += f.x; acc[2 * q + 1] += f.y; } }

__global__ __launch_bounds__(256) void gather_out(const int* __restrict__ csr_src,
                                                  const uint4* __restrict__ desc,
                                                  const uint4* __restrict__ G,
                                                  const float* __restrict__ bias,
                                                  float* __restrict__ O, int N) {
    int gid = blockIdx.x * 256 + threadIdx.x;
    int v = gid >> 3;
    if (v >= N) return;
    int l8 = gid & 7;
    uint4 nd = desc[v];
    unsigned r0 = nd.x;
    unsigned r1 = r0 + nd.y;
    float dv = __uint_as_float(nd.z);
    float acc[8];
#pragma unroll
    for (int i = 0; i < 8; ++i) acc[i] = 0.f;
    {
        uint4 u = G[(size_t)v * 8 + l8];  // self-loop term
        ACCUM8(u)
    }
    unsigned j = r0;   // 16 B aligned
    for (; j + 8 <= r1; j += 8) {
        int4 sa = *(const int4*)(csr_src + j);
        int4 sb = *(const int4*)(csr_src + j + 4);
        const int s[8] = { sa.x, sa.y, sa.z, sa.w, sb.x, sb.y, sb.z, sb.w };
        uint4 u[8];
#pragma unroll
        for (int i = 0; i < 8; ++i) u[i] = G[(size_t)s[i] * 8 + l8];
#pragma unroll
        for (int i = 0; i < 8; ++i) ACCUM8(u[i])
    }
    if (j + 4 <= r1) {
        int4 sa = *(const int4*)(csr_src + j);
        const int s[4] = { sa.x, sa.y, sa.z, sa.w };
        uint4 u[4];
#pragma unroll
        for (int i = 0; i < 4; ++i) u[i] = G[(size_t)s[i] * 8 + l8];
#pragma unroll
        for (int i = 0; i < 4; ++i) ACCUM8(u[i])
        j += 4;
    }
    for (; j < r1; ++j) {
        uint4 u = G[(size_t)csr_src[j] * 8 + l8];
        ACCUM8(u)
    }
    float4 bb0 = ((const float4*)bias)[l8 * 2];
    float4 bb1 = ((const float4*)bias)[l8 * 2 + 1];
    float4* o = (float4*)O + (size_t)v * 16 + l8 * 2;
    o[0] = make_float4(acc[0] * dv + bb0.x, acc[1] * dv + bb0.y,
                       acc[2] * dv + bb0.z, acc[3] * dv + bb0.w);
    o[1] = make_float4(acc[4] * dv + bb1.x, acc[5] * dv + bb1.y,
                       acc[6] * dv + bb1.z, acc[7] * dv + bb1.w);
}
#undef ACCUM8

extern "C" void kernel_launch(void* const* d_in, const int* in_sizes, int n_in,
                              void* d_out, int out_size, void* d_ws, size_t ws_size,
                              hipStream_t stream) {
    const float* x  = (const float*)d_in[0];
    const int*   ei = (const int*)d_in[1];
    const float* W1 = (const float*)d_in[2];
    const float* b1 = (const float*)d_in[3];
    const float* W2 = (const float*)d_in[4];
    const float* b2 = (const float*)d_in[5];
    int N = in_sizes[0] / F;
    int E = in_sizes[1] / 2;
    const int* srcp = ei;
    const int* dstp = ei + E;
    float* out = (float*)d_out;
    int NB = (N + 255) >> 8;

    char* w = (char*)d_ws;
    auto align = [](size_t s) { return (s + 255) / 256 * 256; };
    unsigned* bar     = (unsigned*)w;  w += 256;                         // barriers + work counters
    unsigned* bcnt    = (unsigned*)w;  w += align(NBMAX * 4);
    unsigned* part    = (unsigned*)w;  w += align((size_t)NB << (CAPSH + 2));
    int*      csrsrc  = (int*)w;       w += align((size_t)NB << (CAPSH + 2));
    uint4*    desc    = (uint4*)w;     w += align((size_t)N * 16);
    float*    dinvf   = (float*)w;     w += align((size_t)N * 4);
    __half2*  bufA    = (__half2*)w;   w += align((size_t)N * F * 2);  // g1 (f16, unscaled)
    __half*   bufC    = (__half*)w;    w += align((size_t)N * F * 2);  // g2 (f16, scaled)

    // zero barriers/work-counters + bcnt (contiguous)
    hipMemsetAsync(bar, 0, 256 + align(NBMAX * 4), stream);

    static int g0 = 0;
    if (g0 == 0) {
        int dev = 0; (void)hipGetDevice(&dev);
        int cu = 0; (void)hipDeviceGetAttribute(&cu, hipDeviceAttributeMultiprocessorCount, dev);
        int occ = 0; (void)hipOccupancyMaxActiveBlocksPerMultiprocessor(&occ, fused_abc, 256, 0);
        if (cu <= 0) cu = 256;
        if (occ <= 0) occ = 1;          // smaller grid is always safe (loops just run longer)
        long long g = (long long)occ * cu;
        if (g > 2048) g = 2048;
        if (g < 1) g = 1;
        g0 = (int)g;
    }

    int PG = (E + CHUNK - 1) / CHUNK;
    int MMG = (N + MM2 - 1) / MM2;
    int NVB1 = PG + MMG;
    int NVB3 = (N + GMN - 1) / GMN;

    fused_abc<<<g0, 256, 0, stream>>>(srcp, dstp, bar, bcnt, part, E, NB, PG, NVB1,
                                      x, W1, (__half2*)bufA, desc, csrsrc, dinvf,
                                      b1, W2, bufC, N, NVB3);
    gather_out<<<((size_t)N * 8 + 255) / 256, 256, 0, stream>>>(csrsrc, desc, (const uint4*)bufC, b2, out, N);
}

// Round 3
// 192.035 us; speedup vs baseline: 1.7474x; 1.7474x over previous
//
#include <hip/hip_runtime.h>
#include <hip/hip_fp16.h>

#define F 64
#define NBMAX 1024     // max dst-buckets (256 nodes each) -> supports N <= 262144
#define CHUNK 4096     // edges per partition block
#define CAPSH 13       // bucket capacity = 8192 slots (mean fill ~2560 + align pad <=768)
#define CAP (1 << CAPSH)
#define MMROWS 128
#define XT_PAD 132

// ---- A: dual-role kernel. Blocks [0,PG) partition edges into fixed-stride
// dst-buckets; blocks [PG,PG+MMG) compute g1 = x@W1 (fp16, UNSCALED — dinv
// applied later in build_bucket). The two tasks are data-independent.
__global__ __launch_bounds__(256) void part_mm(const int* __restrict__ src,
                                               const int* __restrict__ dst,
                                               unsigned* __restrict__ bcnt,
                                               unsigned* __restrict__ part,
                                               int E, int NB, int PG,
                                               const float* __restrict__ Xf,
                                               const float* __restrict__ W,
                                               __half2* __restrict__ Y, int N) {
    __shared__ float4 smem4[3136];   // 50176 B union
    int t = threadIdx.x;
    if ((int)blockIdx.x < PG) {
        // ---- partition role ----
        unsigned* lh    = (unsigned*)smem4;          // NBMAX
        unsigned* lbase = lh + NBMAX;                // NBMAX
        int*      dch   = (int*)(lbase + NBMAX);     // CHUNK dst cache (16 KB)
        int e0 = blockIdx.x * CHUNK;
        int nch = min(CHUNK, E - e0);
        for (int b = t; b < NB; b += 256) lh[b] = 0;
        for (int i = t; i < nch; i += 256) dch[i] = dst[e0 + i];
        __syncthreads();
        for (int i = t; i < nch; i += 256)
            atomicAdd(&lh[((unsigned)dch[i]) >> 8], 1u);
        __syncthreads();
        for (int b = t; b < NB; b += 256) {
            unsigned c = lh[b];
            lbase[b] = c ? atomicAdd(&bcnt[b], c) : 0u;
            lh[b] = 0;  // reuse as local cursor
        }
        __syncthreads();
        for (int i = t; i < nch; i += 256) {
            unsigned d = (unsigned)dch[i];
            unsigned b = d >> 8;
            unsigned pos = lbase[b] + atomicAdd(&lh[b], 1u);
            if (pos < CAP)
                part[((size_t)b << CAPSH) + pos] = ((d & 255u) << 24) | (unsigned)src[e0 + i];
        }
        return;
    }
    // ---- mm role ----
    float* Ws = (float*)smem4;       // 4096 floats
    float* XT = Ws + 4096;           // 64*XT_PAD floats
    for (int i = t; i < 1024; i += 256)
        ((float4*)Ws)[i] = ((const float4*)W)[i];
    int row0 = ((int)blockIdx.x - PG) * MMROWS;
    for (int i = t; i < MMROWS * 16; i += 256) {
        int r = i >> 4, kc = (i & 15) * 4;
        float4 v = make_float4(0.f, 0.f, 0.f, 0.f);
        int gr = row0 + r;
        if (gr < N) v = *(const float4*)(Xf + (size_t)gr * F + kc);
        XT[(kc + 0) * XT_PAD + r] = v.x;
        XT[(kc + 1) * XT_PAD + r] = v.y;
        XT[(kc + 2) * XT_PAD + r] = v.z;
        XT[(kc + 3) * XT_PAD + r] = v.w;
    }
    __syncthreads();
    int ty = t >> 3, tx = t & 7;
    float acc[4][8];
#pragma unroll
    for (int i = 0; i < 4; ++i)
#pragma unroll
        for (int j = 0; j < 8; ++j) acc[i][j] = 0.f;
#pragma unroll 4
    for (int k = 0; k < 64; ++k) {
        float4 xr = *(const float4*)&XT[k * XT_PAD + ty * 4];
        float4 w0 = *(const float4*)&Ws[k * 64 + tx * 8];
        float4 w1 = *(const float4*)&Ws[k * 64 + tx * 8 + 4];
        const float* xv = &xr.x;
#pragma unroll
        for (int i = 0; i < 4; ++i) {
            float xs = xv[i];
            acc[i][0] += xs * w0.x; acc[i][1] += xs * w0.y;
            acc[i][2] += xs * w0.z; acc[i][3] += xs * w0.w;
            acc[i][4] += xs * w1.x; acc[i][5] += xs * w1.y;
            acc[i][6] += xs * w1.z; acc[i][7] += xs * w1.w;
        }
    }
#pragma unroll
    for (int i = 0; i < 4; ++i) {
        int gr = row0 + ty * 4 + i;
        if (gr >= N) continue;
        __half2 h[4];
#pragma unroll
        for (int j = 0; j < 4; ++j)
            h[j] = __floats2half2_rn(acc[i][2 * j], acc[i][2 * j + 1]);
        *reinterpret_cast<uint4*>(Y + (size_t)gr * 32 + tx * 4) =
            *reinterpret_cast<uint4*>(h);
    }
}

// ---- B: per-bucket CSR build. Per-node segments padded to 4-slot (16 B)
// alignment so gathers can use int4 index loads. Emits desc(start,deg,dinv),
// csr_src, and scales this bucket's g1 rows in-place by dinv.
__global__ __launch_bounds__(256) void build_bucket(const unsigned* __restrict__ part,
                                                    const unsigned* __restrict__ bcnt,
                                                    uint4* __restrict__ desc,
                                                    int* __restrict__ csr_src,
                                                    uint4* __restrict__ G,   // g1, scaled in place
                                                    int N) {
    __shared__ unsigned cnt[256], off[256], cur[256];
    __shared__ float dvl[256];
    int t = threadIdx.x;
    int b = blockIdx.x;
    unsigned m0 = (unsigned)b << CAPSH;
    unsigned m1 = m0 + min(bcnt[b], (unsigned)CAP);
    cnt[t] = 0;
    __syncthreads();
    for (unsigned j = m0 + t; j < m1; j += 256)
        atomicAdd(&cnt[part[j] >> 24], 1u);
    __syncthreads();
    off[t] = (cnt[t] + 3u) & ~3u;   // pad each segment to multiple of 4 slots
    __syncthreads();
    for (int o = 1; o < 256; o <<= 1) {
        unsigned add = (t >= o) ? off[t - o] : 0u;
        __syncthreads();
        off[t] += add;
        __syncthreads();
    }
    unsigned excl = (t == 0) ? 0u : off[t - 1];
    __syncthreads();
    off[t] = excl;
    cur[t] = 0;
    int v0 = b << 8;
    int v = v0 + t;
    float di = rsqrtf((float)(cnt[t] + 1u));
    dvl[t] = di;
    if (v < N)
        desc[v] = make_uint4(m0 + excl, cnt[t], __float_as_uint(di), 0u);
    __syncthreads();
    for (unsigned j = m0 + t; j < m1; j += 256) {
        unsigned p = part[j];
        unsigned d = p >> 24;
        unsigned pos = atomicAdd(&cur[d], 1u);
        csr_src[m0 + off[d] + pos] = (int)(p & 0xFFFFFFu);
    }
    // ---- scale this bucket's 256 g1 rows by dinv (coalesced uint4 stream) ----
#pragma unroll
    for (int k = 0; k < 8; ++k) {
        int idx = t + k * 256;            // uint4 index within bucket (2048 total)
        int r = idx >> 3;
        int vv = v0 + r;
        if (vv >= N) continue;
        float dv = dvl[r];
        uint4 u = G[(size_t)v0 * 8 + idx];
        __half2* hp = (__half2*)&u;
#pragma unroll
        for (int q = 0; q < 4; ++q) {
            float2 f = __half22float2(hp[q]);
            hp[q] = __floats2half2_rn(f.x * dv, f.y * dv);
        }
        G[(size_t)v0 * 8 + idx] = u;
    }
}

#define ACCUM8(u) { \
    const __half2* hp = reinterpret_cast<const __half2*>(&(u)); \
    _Pragma("unroll") \
    for (int q = 0; q < 4; ++q) { \
        float2 f = __half22float2(hp[q]); \
        acc[2 * q] += f.x; acc[2 * q + 1] += f.y; } }

// ---- C1: standalone layer-1 gather (NO LDS -> max occupancy, max MLP).
// out1[v] = relu(dinv_v*(sum g1[s] + g1[v]) + b1), fp16 output.
// 8 lanes per node, 1 uint4 per lane per edge, 8-edge unroll.
__global__ __launch_bounds__(256) void gather1(const int* __restrict__ csr_src,
                                               const uint4* __restrict__ desc,
                                               const uint4* __restrict__ G,
                                               const float* __restrict__ bias,
                                               __half* __restrict__ O, int N) {
    int gid = blockIdx.x * 256 + threadIdx.x;
    int v = gid >> 3;
    if (v >= N) return;
    int l8 = gid & 7;
    uint4 nd = desc[v];
    unsigned r0 = nd.x;
    unsigned r1 = r0 + nd.y;
    float dv = __uint_as_float(nd.z);
    float acc[8];
#pragma unroll
    for (int i = 0; i < 8; ++i) acc[i] = 0.f;
    {
        uint4 u = G[(size_t)v * 8 + l8];  // self-loop term
        ACCUM8(u)
    }
    unsigned j = r0;   // 16 B aligned
    for (; j + 8 <= r1; j += 8) {
        int4 sa = *(const int4*)(csr_src + j);
        int4 sb = *(const int4*)(csr_src + j + 4);
        const int s[8] = { sa.x, sa.y, sa.z, sa.w, sb.x, sb.y, sb.z, sb.w };
        uint4 u[8];
#pragma unroll
        for (int i = 0; i < 8; ++i) u[i] = G[(size_t)s[i] * 8 + l8];
#pragma unroll
        for (int i = 0; i < 8; ++i) ACCUM8(u[i])
    }
    if (j + 4 <= r1) {
        int4 sa = *(const int4*)(csr_src + j);
        const int s[4] = { sa.x, sa.y, sa.z, sa.w };
        uint4 u[4];
#pragma unroll
        for (int i = 0; i < 4; ++i) u[i] = G[(size_t)s[i] * 8 + l8];
#pragma unroll
        for (int i = 0; i < 4; ++i) ACCUM8(u[i])
        j += 4;
    }
    for (; j < r1; ++j) {
        uint4 u = G[(size_t)csr_src[j] * 8 + l8];
        ACCUM8(u)
    }
    float4 bb0 = ((const float4*)bias)[l8 * 2];
    float4 bb1 = ((const float4*)bias)[l8 * 2 + 1];
    __half2 h[4];
    h[0] = __floats2half2_rn(fmaxf(acc[0] * dv + bb0.x, 0.f), fmaxf(acc[1] * dv + bb0.y, 0.f));
    h[1] = __floats2half2_rn(fmaxf(acc[2] * dv + bb0.z, 0.f), fmaxf(acc[3] * dv + bb0.w, 0.f));
    h[2] = __floats2half2_rn(fmaxf(acc[4] * dv + bb1.x, 0.f), fmaxf(acc[5] * dv + bb1.y, 0.f));
    h[3] = __floats2half2_rn(fmaxf(acc[6] * dv + bb1.z, 0.f), fmaxf(acc[7] * dv + bb1.w, 0.f));
    *(uint4*)(O + (size_t)v * F + l8 * 8) = *reinterpret_cast<uint4*>(h);
}

// ---- C2: g2 = (out1 @ W2) * dinv  (fp16 in, fp16 out; 64 rows/block) ----
__global__ __launch_bounds__(256, 4) void mm2(const __half* __restrict__ X1,
                                              const float* __restrict__ W,
                                              const uint4* __restrict__ desc,
                                              __half* __restrict__ Y, int N) {
    __shared__ float Ws[64 * 64];     // 16 KB
    __shared__ __half XT[64 * 72];    // 9 KB
    int t = threadIdx.x;
    for (int i = t; i < 1024; i += 256)
        ((float4*)Ws)[i] = ((const float4*)W)[i];
    int row0 = blockIdx.x * 64;
    for (int i = t; i < 512; i += 256) {          // stage 64 fp16 rows (8 KB)
        int r = i >> 3, c = i & 7;
        int gr = row0 + r;
        uint4 u = make_uint4(0u, 0u, 0u, 0u);
        if (gr < N) u = ((const uint4*)X1)[(size_t)gr * 8 + c];
        *(uint4*)&XT[r * 72 + c * 8] = u;
    }
    __syncthreads();
    int tx = t & 7, ty = t >> 3;
    const __half2* Xa = (const __half2*)&XT[ty * 72];
    const __half2* Xb = (const __half2*)&XT[(ty + 32) * 72];
    float a0[8], a1[8];
#pragma unroll
    for (int i = 0; i < 8; ++i) { a0[i] = 0.f; a1[i] = 0.f; }
#pragma unroll 4
    for (int k2 = 0; k2 < 32; ++k2) {
        float2 f0 = __half22float2(Xa[k2]);
        float2 f1 = __half22float2(Xb[k2]);
        int k = 2 * k2;
        float4 w00 = *(const float4*)&Ws[k * 64 + tx * 8];
        float4 w01 = *(const float4*)&Ws[k * 64 + tx * 8 + 4];
        float4 w10 = *(const float4*)&Ws[(k + 1) * 64 + tx * 8];
        float4 w11 = *(const float4*)&Ws[(k + 1) * 64 + tx * 8 + 4];
        a0[0] += f0.x * w00.x + f0.y * w10.x; a0[1] += f0.x * w00.y + f0.y * w10.y;
        a0[2] += f0.x * w00.z + f0.y * w10.z; a0[3] += f0.x * w00.w + f0.y * w10.w;
        a0[4] += f0.x * w01.x + f0.y * w11.x; a0[5] += f0.x * w01.y + f0.y * w11.y;
        a0[6] += f0.x * w01.z + f0.y * w11.z; a0[7] += f0.x * w01.w + f0.y * w11.w;
        a1[0] += f1.x * w00.x + f1.y * w10.x; a1[1] += f1.x * w00.y + f1.y * w10.y;
        a1[2] += f1.x * w00.z + f1.y * w10.z; a1[3] += f1.x * w00.w + f1.y * w10.w;
        a1[4] += f1.x * w01.x + f1.y * w11.x; a1[5] += f1.x * w01.y + f1.y * w11.y;
        a1[6] += f1.x * w01.z + f1.y * w11.z; a1[7] += f1.x * w01.w + f1.y * w11.w;
    }
#pragma unroll
    for (int half_ = 0; half_ < 2; ++half_) {
        int r = ty + half_ * 32;
        int v = row0 + r;
        if (v >= N) continue;
        float dv = __uint_as_float(((const unsigned*)desc)[4 * (size_t)v + 2]);
        const float* a = half_ ? a1 : a0;
        __half2 h[4];
#pragma unroll
        for (int q = 0; q < 4; ++q)
            h[q] = __floats2half2_rn(a[2 * q] * dv, a[2 * q + 1] * dv);
        *(uint4*)(Y + (size_t)v * F + tx * 8) = *reinterpret_cast<uint4*>(h);
    }
}

// ---- D: final gather: out[v] = dinv[v]*(sum g2[s] + g2[v]) + b2 ; fp32 out ----
__global__ __launch_bounds__(256) void gather_out(const int* __restrict__ csr_src,
                                                  const uint4* __restrict__ desc,
                                                  const uint4* __restrict__ G,
                                                  const float* __restrict__ bias,
                                                  float* __restrict__ O, int N) {
    int gid = blockIdx.x * 256 + threadIdx.x;
    int v = gid >> 3;
    if (v >= N) return;
    int l8 = gid & 7;
    uint4 nd = desc[v];
    unsigned r0 = nd.x;
    unsigned r1 = r0 + nd.y;
    float dv = __uint_as_float(nd.z);
    float acc[8];
#pragma unroll
    for (int i = 0; i < 8; ++i) acc[i] = 0.f;
    {
        uint4 u = G[(size_t)v * 8 + l8];  // self-loop term
        ACCUM8(u)
    }
    unsigned j = r0;   // 16 B aligned
    for (; j + 8 <= r1; j += 8) {
        int4 sa = *(const int4*)(csr_src + j);
        int4 sb = *(const int4*)(csr_src + j + 4);
        const int s[8] = { sa.x, sa.y, sa.z, sa.w, sb.x, sb.y, sb.z, sb.w };
        uint4 u[8];
#pragma unroll
        for (int i = 0; i < 8; ++i) u[i] = G[(size_t)s[i] * 8 + l8];
#pragma unroll
        for (int i = 0; i < 8; ++i) ACCUM8(u[i])
    }
    if (j + 4 <= r1) {
        int4 sa = *(const int4*)(csr_src + j);
        const int s[4] = { sa.x, sa.y, sa.z, sa.w };
        uint4 u[4];
#pragma unroll
        for (int i = 0; i < 4; ++i) u[i] = G[(size_t)s[i] * 8 + l8];
#pragma unroll
        for (int i = 0; i < 4; ++i) ACCUM8(u[i])
        j += 4;
    }
    for (; j < r1; ++j) {
        uint4 u = G[(size_t)csr_src[j] * 8 + l8];
        ACCUM8(u)
    }
    float4 bb0 = ((const float4*)bias)[l8 * 2];
    float4 bb1 = ((const float4*)bias)[l8 * 2 + 1];
    float4* o = (float4*)O + (size_t)v * 16 + l8 * 2;
    o[0] = make_float4(acc[0] * dv + bb0.x, acc[1] * dv + bb0.y,
                       acc[2] * dv + bb0.z, acc[3] * dv + bb0.w);
    o[1] = make_float4(acc[4] * dv + bb1.x, acc[5] * dv + bb1.y,
                       acc[6] * dv + bb1.z, acc[7] * dv + bb1.w);
}
#undef ACCUM8

extern "C" void kernel_launch(void* const* d_in, const int* in_sizes, int n_in,
                              void* d_out, int out_size, void* d_ws, size_t ws_size,
                              hipStream_t stream) {
    const float* x  = (const float*)d_in[0];
    const int*   ei = (const int*)d_in[1];
    const float* W1 = (const float*)d_in[2];
    const float* b1 = (const float*)d_in[3];
    const float* W2 = (const float*)d_in[4];
    const float* b2 = (const float*)d_in[5];
    int N = in_sizes[0] / F;
    int E = in_sizes[1] / 2;
    const int* srcp = ei;
    const int* dstp = ei + E;
    float* out = (float*)d_out;
    int NB = (N + 255) >> 8;

    char* w = (char*)d_ws;
    auto align = [](size_t s) { return (s + 255) / 256 * 256; };
    unsigned* bcnt    = (unsigned*)w;  w += align(NBMAX * 4);
    unsigned* part    = (unsigned*)w;  w += align((size_t)NB << (CAPSH + 2));
    int*      csrsrc  = (int*)w;       w += align((size_t)NB << (CAPSH + 2));
    uint4*    desc    = (uint4*)w;     w += align((size_t)N * 16);
    __half2*  bufA    = (__half2*)w;   w += align((size_t)N * F * 2);  // g1 (f16, dinv-scaled)
    __half*   bufB    = (__half*)w;    w += align((size_t)N * F * 2);  // out1 (f16)
    __half*   bufC    = (__half*)w;    w += align((size_t)N * F * 2);  // g2 (f16)

    hipMemsetAsync(bcnt, 0, (size_t)NB * 4, stream);

    int PG = (E + CHUNK - 1) / CHUNK;
    int MMG = (N + MMROWS - 1) / MMROWS;
    // A: partition edges (blocks 0..PG) + g1 = x@W1 unscaled (blocks PG..PG+MMG)
    part_mm<<<PG + MMG, 256, 0, stream>>>(srcp, dstp, bcnt, part, E, NB, PG,
                                          x, W1, (__half2*)bufA, N);
    // B: CSR build (4-aligned segments) + desc + in-place dinv scaling of g1
    build_bucket<<<NB, 256, 0, stream>>>(part, bcnt, desc, csrsrc, (uint4*)bufA, N);
    // C1: out1 = relu(dinv*(sum g1 + self)+b1)  — high-occupancy gather
    gather1<<<(int)(((size_t)N * 8 + 255) / 256), 256, 0, stream>>>(
        csrsrc, desc, (const uint4*)bufA, b1, bufB, N);
    // C2: g2 = (out1@W2)*dinv
    mm2<<<(N + 63) / 64, 256, 0, stream>>>(bufB, W2, desc, bufC, N);
    // D: out = dinv*(sum g2 + self) + b2
    gather_out<<<(int)(((size_t)N * 8 + 255) / 256), 256, 0, stream>>>(
        csrsrc, desc, (const uint4*)bufC, b2, out, N);
}

// Round 4
// 185.730 us; speedup vs baseline: 1.8067x; 1.0340x over previous
//
#include <hip/hip_runtime.h>
#include <hip/hip_fp16.h>

#define F 64
#define NBMAX 1024     // max dst-buckets (256 nodes each) -> supports N <= 262144
#define CHUNK 4096     // edges per partition block
#define CAPSH 13       // bucket capacity = 8192 slots (mean fill ~2560 + align pad <=768)
#define CAP (1 << CAPSH)
#define MMROWS 128
#define XT_PAD 132
#define GMN 64         // nodes per fused gather_mm block

// ---- A: dual-role kernel. Blocks [0,PG) partition edges into fixed-stride
// dst-buckets; blocks [PG,PG+MMG) compute g1 = x@W1 (fp16, UNSCALED — dinv
// is applied per-edge in the gather via dinvf[] fma).
__global__ __launch_bounds__(256) void part_mm(const int* __restrict__ src,
                                               const int* __restrict__ dst,
                                               unsigned* __restrict__ bcnt,
                                               unsigned* __restrict__ part,
                                               int E, int NB, int PG,
                                               const float* __restrict__ Xf,
                                               const float* __restrict__ W,
                                               __half2* __restrict__ Y, int N) {
    __shared__ float4 smem4[3136];   // 50176 B union
    int t = threadIdx.x;
    if ((int)blockIdx.x < PG) {
        // ---- partition role ----
        unsigned* lh    = (unsigned*)smem4;          // NBMAX
        unsigned* lbase = lh + NBMAX;                // NBMAX
        int*      dch   = (int*)(lbase + NBMAX);     // CHUNK dst cache (16 KB)
        int e0 = blockIdx.x * CHUNK;
        int nch = min(CHUNK, E - e0);
        for (int b = t; b < NB; b += 256) lh[b] = 0;
        for (int i = t; i < nch; i += 256) dch[i] = dst[e0 + i];
        __syncthreads();
        for (int i = t; i < nch; i += 256)
            atomicAdd(&lh[((unsigned)dch[i]) >> 8], 1u);
        __syncthreads();
        for (int b = t; b < NB; b += 256) {
            unsigned c = lh[b];
            lbase[b] = c ? atomicAdd(&bcnt[b], c) : 0u;
            lh[b] = 0;  // reuse as local cursor
        }
        __syncthreads();
        for (int i = t; i < nch; i += 256) {
            unsigned d = (unsigned)dch[i];
            unsigned b = d >> 8;
            unsigned pos = lbase[b] + atomicAdd(&lh[b], 1u);
            if (pos < CAP)
                part[((size_t)b << CAPSH) + pos] = ((d & 255u) << 24) | (unsigned)src[e0 + i];
        }
        return;
    }
    // ---- mm role ----
    float* Ws = (float*)smem4;       // 4096 floats
    float* XT = Ws + 4096;           // 64*XT_PAD floats
    for (int i = t; i < 1024; i += 256)
        ((float4*)Ws)[i] = ((const float4*)W)[i];
    int row0 = ((int)blockIdx.x - PG) * MMROWS;
    for (int i = t; i < MMROWS * 16; i += 256) {
        int r = i >> 4, kc = (i & 15) * 4;
        float4 v = make_float4(0.f, 0.f, 0.f, 0.f);
        int gr = row0 + r;
        if (gr < N) v = *(const float4*)(Xf + (size_t)gr * F + kc);
        XT[(kc + 0) * XT_PAD + r] = v.x;
        XT[(kc + 1) * XT_PAD + r] = v.y;
        XT[(kc + 2) * XT_PAD + r] = v.z;
        XT[(kc + 3) * XT_PAD + r] = v.w;
    }
    __syncthreads();
    int ty = t >> 3, tx = t & 7;
    float acc[4][8];
#pragma unroll
    for (int i = 0; i < 4; ++i)
#pragma unroll
        for (int j = 0; j < 8; ++j) acc[i][j] = 0.f;
#pragma unroll 4
    for (int k = 0; k < 64; ++k) {
        float4 xr = *(const float4*)&XT[k * XT_PAD + ty * 4];
        float4 w0 = *(const float4*)&Ws[k * 64 + tx * 8];
        float4 w1 = *(const float4*)&Ws[k * 64 + tx * 8 + 4];
        const float* xv = &xr.x;
#pragma unroll
        for (int i = 0; i < 4; ++i) {
            float xs = xv[i];
            acc[i][0] += xs * w0.x; acc[i][1] += xs * w0.y;
            acc[i][2] += xs * w0.z; acc[i][3] += xs * w0.w;
            acc[i][4] += xs * w1.x; acc[i][5] += xs * w1.y;
            acc[i][6] += xs * w1.z; acc[i][7] += xs * w1.w;
        }
    }
#pragma unroll
    for (int i = 0; i < 4; ++i) {
        int gr = row0 + ty * 4 + i;
        if (gr >= N) continue;
        __half2 h[4];
#pragma unroll
        for (int j = 0; j < 4; ++j)
            h[j] = __floats2half2_rn(acc[i][2 * j], acc[i][2 * j + 1]);
        *reinterpret_cast<uint4*>(Y + (size_t)gr * 32 + tx * 4) =
            *reinterpret_cast<uint4*>(h);
    }
}

// ---- B: per-bucket CSR build, 1024 threads (16 waves) per block for 4x the
// parallelism of the old 256-thread version. Per-node segments padded to
// 4-slot (16 B) alignment. Emits desc(start,deg,dinv), dinvf, csr_src.
// NO g1 rescale (dinv applied in gather via fma).
__global__ __launch_bounds__(1024) void build_bucket(const unsigned* __restrict__ part,
                                                     const unsigned* __restrict__ bcnt,
                                                     uint4* __restrict__ desc,
                                                     int* __restrict__ csr_src,
                                                     float* __restrict__ dinvf,
                                                     int N) {
    __shared__ unsigned cnt[256], off[256], cur[256];
    int t = threadIdx.x;
    int b = blockIdx.x;
    unsigned m0 = (unsigned)b << CAPSH;
    unsigned m1 = m0 + min(bcnt[b], (unsigned)CAP);
    if (t < 256) cnt[t] = 0;
    __syncthreads();
    for (unsigned j = m0 + t; j < m1; j += 1024)
        atomicAdd(&cnt[part[j] >> 24], 1u);
    __syncthreads();
    if (t < 256) off[t] = (cnt[t] + 3u) & ~3u;   // pad segments to 4 slots
    __syncthreads();
    for (int o = 1; o < 256; o <<= 1) {
        unsigned add = 0;
        if (t < 256 && t >= o) add = off[t - o];
        __syncthreads();
        if (t < 256) off[t] += add;
        __syncthreads();
    }
    if (t < 256) {
        unsigned excl = t ? off[t - 1] : 0u;
        unsigned c = cnt[t];
        int v = (b << 8) + t;
        float di = rsqrtf((float)(c + 1u));
        if (v < N) {
            desc[v] = make_uint4(m0 + excl, c, __float_as_uint(di), 0u);
            dinvf[v] = di;
        }
        // note: off currently holds inclusive scan; rewrite to exclusive AFTER
        // all lanes read off[t-1] — barrier below orders this.
        cur[t] = 0;
        off[t] = excl;
    }
    __syncthreads();
    for (unsigned j = m0 + t; j < m1; j += 1024) {
        unsigned p = part[j];
        unsigned d = p >> 24;
        unsigned pos = atomicAdd(&cur[d], 1u);
        csr_src[m0 + off[d] + pos] = (int)(p & 0xFFFFFFu);
    }
}

// accumulate 4x half2 into 8 fp32 with per-row weight (cvt+fma)
__device__ __forceinline__ void acc8f(float* a, const uint4& u, float w) {
    const __half2* hp = reinterpret_cast<const __half2*>(&u);
#pragma unroll
    for (int q = 0; q < 4; ++q) {
        float2 f = __half22float2(hp[q]);
        a[2 * q]     += f.x * w;
        a[2 * q + 1] += f.y * w;
    }
}

// ---- C FUSED: out1[v] = relu(dinv_v*(sum dinv_s*g1[s] + dinv_v*g1[v]) + b1);
//               g2 = (out1@W2)*dinv_v  (fp16)
__global__ __launch_bounds__(256, 4) void gather_mm(const int* __restrict__ csr_src,
                                                    const uint4* __restrict__ desc,
                                                    const uint4* __restrict__ G,
                                                    const float* __restrict__ dinvf,
                                                    const float* __restrict__ bias,
                                                    const float* __restrict__ W,
                                                    __half* __restrict__ Y, int N) {
    __shared__ float Ws[64 * 64];     // 16 KB
    __shared__ __half XT[64 * 72];    // 9 KB
    __shared__ float dvs[64];
    int t = threadIdx.x;
    for (int i = t; i < 1024; i += 256)
        ((float4*)Ws)[i] = ((const float4*)W)[i];
    int v0 = blockIdx.x * GMN;
    {   // ---- phase 1: gather with per-edge dinv[src] fma ----
        int grp = t >> 2, l4 = t & 3;
        int v = v0 + grp;
        float acc[16];
#pragma unroll
        for (int i = 0; i < 16; ++i) acc[i] = 0.f;
        float dv = 0.f;
        if (v < N) {
            uint4 nd = desc[v];
            unsigned r0 = nd.x, r1 = nd.x + nd.y;
            dv = __uint_as_float(nd.z);
            size_t gb = (size_t)v * 8 + l4 * 2;
            uint4 sa = G[gb], sb = G[gb + 1];   // self-loop: weight dinv_v
            acc8f(acc, sa, dv); acc8f(acc + 8, sb, dv);
            unsigned j = r0;
            for (; j + 4 <= r1; j += 4) {
                int4 s4 = *(const int4*)(csr_src + j);
                const int s[4] = { s4.x, s4.y, s4.z, s4.w };
                float dw[4];
                uint4 u[4][2];
#pragma unroll
                for (int i = 0; i < 4; ++i) {
                    size_t base = (size_t)s[i] * 8 + l4 * 2;
                    u[i][0] = G[base]; u[i][1] = G[base + 1];
                    dw[i] = dinvf[s[i]];
                }
#pragma unroll
                for (int i = 0; i < 4; ++i) {
                    acc8f(acc, u[i][0], dw[i]);
                    acc8f(acc + 8, u[i][1], dw[i]);
                }
            }
            for (; j < r1; ++j) {
                int sj = csr_src[j];
                float dwj = dinvf[sj];
                size_t base = (size_t)sj * 8 + l4 * 2;
                uint4 a = G[base], b = G[base + 1];
                acc8f(acc, a, dwj); acc8f(acc + 8, b, dwj);
            }
        }
        if (l4 == 0) dvs[grp] = dv;
        __half h[16];
#pragma unroll
        for (int q = 0; q < 4; ++q) {
            float4 bb = ((const float4*)bias)[l4 * 4 + q];
            float r0_ = fmaxf(acc[4 * q + 0] * dv + bb.x, 0.f);
            float r1_ = fmaxf(acc[4 * q + 1] * dv + bb.y, 0.f);
            float r2_ = fmaxf(acc[4 * q + 2] * dv + bb.z, 0.f);
            float r3_ = fmaxf(acc[4 * q + 3] * dv + bb.w, 0.f);
            ((__half2*)h)[2 * q + 0] = __floats2half2_rn(r0_, r1_);
            ((__half2*)h)[2 * q + 1] = __floats2half2_rn(r2_, r3_);
        }
        *(uint4*)&XT[grp * 72 + l4 * 16] = ((uint4*)h)[0];
        *(uint4*)&XT[grp * 72 + l4 * 16 + 8] = ((uint4*)h)[1];
    }
    __syncthreads();
    // ---- phase 2: mm (2 rows x 8 cols per thread) ----
    int tx = t & 7, ty = t >> 3;
    const __half2* Xa = (const __half2*)&XT[ty * 72];
    const __half2* Xb = (const __half2*)&XT[(ty + 32) * 72];
    float a0[8], a1[8];
#pragma unroll
    for (int i = 0; i < 8; ++i) { a0[i] = 0.f; a1[i] = 0.f; }
#pragma unroll 4
    for (int k2 = 0; k2 < 32; ++k2) {
        float2 f0 = __half22float2(Xa[k2]);
        float2 f1 = __half22float2(Xb[k2]);
        int k = 2 * k2;
        float4 w00 = *(const float4*)&Ws[k * 64 + tx * 8];
        float4 w01 = *(const float4*)&Ws[k * 64 + tx * 8 + 4];
        float4 w10 = *(const float4*)&Ws[(k + 1) * 64 + tx * 8];
        float4 w11 = *(const float4*)&Ws[(k + 1) * 64 + tx * 8 + 4];
        a0[0] += f0.x * w00.x + f0.y * w10.x; a0[1] += f0.x * w00.y + f0.y * w10.y;
        a0[2] += f0.x * w00.z + f0.y * w10.z; a0[3] += f0.x * w00.w + f0.y * w10.w;
        a0[4] += f0.x * w01.x + f0.y * w11.x; a0[5] += f0.x * w01.y + f0.y * w11.y;
        a0[6] += f0.x * w01.z + f0.y * w11.z; a0[7] += f0.x * w01.w + f0.y * w11.w;
        a1[0] += f1.x * w00.x + f1.y * w10.x; a1[1] += f1.x * w00.y + f1.y * w10.y;
        a1[2] += f1.x * w00.z + f1.y * w10.z; a1[3] += f1.x * w00.w + f1.y * w10.w;
        a1[4] += f1.x * w01.x + f1.y * w11.x; a1[5] += f1.x * w01.y + f1.y * w11.y;
        a1[6] += f1.x * w01.z + f1.y * w11.z; a1[7] += f1.x * w01.w + f1.y * w11.w;
    }
#pragma unroll
    for (int half_ = 0; half_ < 2; ++half_) {
        int r = ty + half_ * 32;
        int v = v0 + r;
        if (v >= N) continue;
        float dv = dvs[r];
        const float* a = half_ ? a1 : a0;
        __half2 h[4];
#pragma unroll
        for (int q = 0; q < 4; ++q)
            h[q] = __floats2half2_rn(a[2 * q] * dv, a[2 * q + 1] * dv);
        *(uint4*)(Y + (size_t)v * F + tx * 8) = *reinterpret_cast<uint4*>(h);
    }
}

// ---- D: final gather: out[v] = dinv[v]*(sum g2[s] + g2[v]) + b2 ; fp32 out ----
#define ACCUM8(u) { \
    const __half2* hp = reinterpret_cast<const __half2*>(&(u)); \
    _Pragma("unroll") \
    for (int q = 0; q < 4; ++q) { \
        float2 f = __half22float2(hp[q]); \
        acc[2 * q] += f.x; acc[2 * q + 1] += f.y; } }

__global__ __launch_bounds__(256) void gather_out(const int* __restrict__ csr_src,
                                                  const uint4* __restrict__ desc,
                                                  const uint4* __restrict__ G,
                                                  const float* __restrict__ bias,
                                                  float* __restrict__ O, int N) {
    int gid = blockIdx.x * 256 + threadIdx.x;
    int v = gid >> 3;
    if (v >= N) return;
    int l8 = gid & 7;
    uint4 nd = desc[v];
    unsigned r0 = nd.x;
    unsigned r1 = r0 + nd.y;
    float dv = __uint_as_float(nd.z);
    float acc[8];
#pragma unroll
    for (int i = 0; i < 8; ++i) acc[i] = 0.f;
    {
        uint4 u = G[(size_t)v * 8 + l8];  // self-loop term (g2 has dinv baked in)
        ACCUM8(u)
    }
    unsigned j = r0;   // 16 B aligned
    for (; j + 8 <= r1; j += 8) {
        int4 sa = *(const int4*)(csr_src + j);
        int4 sb = *(const int4*)(csr_src + j + 4);
        const int s[8] = { sa.x, sa.y, sa.z, sa.w, sb.x, sb.y, sb.z, sb.w };
        uint4 u[8];
#pragma unroll
        for (int i = 0; i < 8; ++i) u[i] = G[(size_t)s[i] * 8 + l8];
#pragma unroll
        for (int i = 0; i < 8; ++i) ACCUM8(u[i])
    }
    if (j + 4 <= r1) {
        int4 sa = *(const int4*)(csr_src + j);
        const int s[4] = { sa.x, sa.y, sa.z, sa.w };
        uint4 u[4];
#pragma unroll
        for (int i = 0; i < 4; ++i) u[i] = G[(size_t)s[i] * 8 + l8];
#pragma unroll
        for (int i = 0; i < 4; ++i) ACCUM8(u[i])
        j += 4;
    }
    for (; j < r1; ++j) {
        uint4 u = G[(size_t)csr_src[j] * 8 + l8];
        ACCUM8(u)
    }
    float4 bb0 = ((const float4*)bias)[l8 * 2];
    float4 bb1 = ((const float4*)bias)[l8 * 2 + 1];
    float4* o = (float4*)O + (size_t)v * 16 + l8 * 2;
    o[0] = make_float4(acc[0] * dv + bb0.x, acc[1] * dv + bb0.y,
                       acc[2] * dv + bb0.z, acc[3] * dv + bb0.w);
    o[1] = make_float4(acc[4] * dv + bb1.x, acc[5] * dv + bb1.y,
                       acc[6] * dv + bb1.z, acc[7] * dv + bb1.w);
}
#undef ACCUM8

extern "C" void kernel_launch(void* const* d_in, const int* in_sizes, int n_in,
                              void* d_out, int out_size, void* d_ws, size_t ws_size,
                              hipStream_t stream) {
    const float* x  = (const float*)d_in[0];
    const int*   ei = (const int*)d_in[1];
    const float* W1 = (const float*)d_in[2];
    const float* b1 = (const float*)d_in[3];
    const float* W2 = (const float*)d_in[4];
    const float* b2 = (const float*)d_in[5];
    int N = in_sizes[0] / F;
    int E = in_sizes[1] / 2;
    const int* srcp = ei;
    const int* dstp = ei + E;
    float* out = (float*)d_out;
    int NB = (N + 255) >> 8;

    char* w = (char*)d_ws;
    auto align = [](size_t s) { return (s + 255) / 256 * 256; };
    unsigned* bcnt    = (unsigned*)w;  w += align(NBMAX * 4);
    unsigned* part    = (unsigned*)w;  w += align((size_t)NB << (CAPSH + 2));
    int*      csrsrc  = (int*)w;       w += align((size_t)NB << (CAPSH + 2));
    uint4*    desc    = (uint4*)w;     w += align((size_t)N * 16);
    float*    dinvf   = (float*)w;     w += align((size_t)N * 4);
    __half2*  bufA    = (__half2*)w;   w += align((size_t)N * F * 2);  // g1 (f16, UNSCALED)
    __half*   bufC    = (__half*)w;    w += align((size_t)N * F * 2);  // g2 (f16, dinv-scaled)

    hipMemsetAsync(bcnt, 0, (size_t)NB * 4, stream);

    int PG = (E + CHUNK - 1) / CHUNK;
    int MMG = (N + MMROWS - 1) / MMROWS;
    // A: partition edges (blocks 0..PG) + g1 = x@W1 unscaled (blocks PG..PG+MMG)
    part_mm<<<PG + MMG, 256, 0, stream>>>(srcp, dstp, bcnt, part, E, NB, PG,
                                          x, W1, (__half2*)bufA, N);
    // B: CSR build (4-aligned segments) + desc + dinvf (1024 thr, no rescale)
    build_bucket<<<NB, 1024, 0, stream>>>(part, bcnt, desc, csrsrc, dinvf, N);
    // C: out1 = relu(dinv*(sum dinv_s*g1[s] + dinv_v*g1[v])+b1); g2 = (out1@W2)*dinv
    gather_mm<<<(N + GMN - 1) / GMN, 256, 0, stream>>>(csrsrc, desc, (const uint4*)bufA,
                                                       dinvf, b1, W2, bufC, N);
    // D: out = dinv*(sum g2 + self) + b2
    gather_out<<<(int)(((size_t)N * 8 + 255) / 256), 256, 0, stream>>>(
        csrsrc, desc, (const uint4*)bufC, b2, out, N);
}